// Round 13
// baseline (117.728 us; speedup 1.0000x reference)
//
#include <hip/hip_runtime.h>

// Sinkhorn on 8192 independent 64x64 f32 matrices, 2 waves/matrix,
// 2 matrices per 256-thread block (R10 skeleton), with K/u/v stored as
// PACKED f16 and the dots done by v_dot2_f32_f16 (f32 accumulate):
//   - one v_readlane (4 cyc) now carries TWO broadcast values
//   - one fdot2 (2 cyc) does TWO fma-terms
// halving the dominant RL stream and halving K register footprint
// (64 f32 -> 32 packed regs) for higher occupancy. Updates stay f32.
// Wave h owns: rows 32h..32h+31 (col copy cH, col=lane) and the 32-col
// slice 32h.. of row `lane` (row copy rH). u/v live as f16 pairs: lane l
// (l&31) holds indices 2l,2l+1; RL index 16h+t fetches pair 32h+2t.

static constexpr int   kIters = 20;
static constexpr float kEps   = 1e-6f;

typedef _Float16 h2 __attribute__((ext_vector_type(2)));

__device__ __forceinline__ float RLf(float x, int l) {
    return __int_as_float(__builtin_amdgcn_readlane(__float_as_int(x), l));
}
__device__ __forceinline__ h2 RLh2(h2 x, int l) {
    int bits;
    __builtin_memcpy(&bits, &x, 4);
    int r = __builtin_amdgcn_readlane(bits, l);
    h2 out;
    __builtin_memcpy(&out, &r, 4);
    return out;
}

__global__ __launch_bounds__(256) void sinkhorn64_h2(const float* __restrict__ in,
                                                     float* __restrict__ out) {
    __shared__ float xb0[2][2][64];   // [matrix-pair][half][slot]
    __shared__ float xb1[2][2][64];
    const int tid  = threadIdx.x;
    const int wid  = tid >> 6;
    const int p    = wid >> 1;               // which matrix in this block
    const int h    = wid & 1;                // which half this wave owns
    const int lane = tid & 63;
    const int pl   = lane & 31;              // pair slot this lane updates
    const long m   = (long)blockIdx.x * 2 + p;
    const float* __restrict__ A = in  + m * 4096;
    float* __restrict__ O       = out + m * 4096;

    // ---- row copy: f32 load, row-max exchange, exp, pack to f16 pairs ----
    float rKf[32];
#pragma unroll
    for (int k4 = 0; k4 < 8; ++k4) {
        const float4 f = *reinterpret_cast<const float4*>(A + (lane << 6) + 32 * h + (k4 << 2));
        rKf[4 * k4 + 0] = f.x; rKf[4 * k4 + 1] = f.y;
        rKf[4 * k4 + 2] = f.z; rKf[4 * k4 + 3] = f.w;
    }
    float pm = rKf[0];
#pragma unroll
    for (int k = 1; k < 32; ++k) pm = fmaxf(pm, rKf[k]);
    xb0[p][h][lane] = pm;
    __syncthreads();
    const float mx = fmaxf(pm, xb0[p][1 - h][lane]);   // full max of row `lane`

    h2 rH[16];
#pragma unroll
    for (int t = 0; t < 16; ++t) {
        rH[t].x = (_Float16)__expf(rKf[2 * t + 0] - mx);
        rH[t].y = (_Float16)__expf(rKf[2 * t + 1] - mx);
    }

    // ---- col copy: load rows 32h+i, exp with broadcast row-max, pack ----
    h2 cH[16];
#pragma unroll
    for (int t = 0; t < 16; ++t) {
        const float x0 = A[((32 * h + 2 * t + 0) << 6) + lane];
        const float x1 = A[((32 * h + 2 * t + 1) << 6) + lane];
        cH[t].x = (_Float16)__expf(x0 - RLf(mx, 32 * h + 2 * t + 0));
        cH[t].y = (_Float16)__expf(x1 - RLf(mx, 32 * h + 2 * t + 1));
    }

    // u/v packed pairs: lane pl holds indices 2pl, 2pl+1.
    h2 up; up.x = (_Float16)1.0f; up.y = (_Float16)1.0f;
    h2 vp = up;
    const int rlbase = 16 * h;

#pragma unroll 1
    for (int it = 0; it < kIters; ++it) {
        // ---- w partial: (K v)_{row=lane} over own 32 cols, f32 accum ----
        {
            float a0 = 0.f, a1 = 0.f, a2 = 0.f, a3 = 0.f;
#pragma unroll
            for (int t = 0; t < 16; t += 4) {
                a0 = __builtin_amdgcn_fdot2(rH[t + 0], RLh2(vp, rlbase + t + 0), a0, false);
                a1 = __builtin_amdgcn_fdot2(rH[t + 1], RLh2(vp, rlbase + t + 1), a1, false);
                a2 = __builtin_amdgcn_fdot2(rH[t + 2], RLh2(vp, rlbase + t + 2), a2, false);
                a3 = __builtin_amdgcn_fdot2(rH[t + 3], RLh2(vp, rlbase + t + 3), a3, false);
            }
            xb1[p][h][lane] = (a0 + a1) + (a2 + a3);
        }
        __syncthreads();
        // ---- u pair update: rows 2pl, 2pl+1 ----
        {
            const float2 a = *reinterpret_cast<const float2*>(&xb1[p][0][2 * pl]);
            const float2 b = *reinterpret_cast<const float2*>(&xb1[p][1][2 * pl]);
            float u0 = (float)up.x, u1 = (float)up.y;
            u0 = u0 * __builtin_amdgcn_rcpf(fmaf(u0, a.x + b.x, kEps));
            u1 = u1 * __builtin_amdgcn_rcpf(fmaf(u1, a.y + b.y, kEps));
            up.x = (_Float16)u0; up.y = (_Float16)u1;
        }

        // ---- t partial: (K^T u)_{col=lane} over own 32 rows ----
        {
            float a0 = 0.f, a1 = 0.f, a2 = 0.f, a3 = 0.f;
#pragma unroll
            for (int t = 0; t < 16; t += 4) {
                a0 = __builtin_amdgcn_fdot2(cH[t + 0], RLh2(up, rlbase + t + 0), a0, false);
                a1 = __builtin_amdgcn_fdot2(cH[t + 1], RLh2(up, rlbase + t + 1), a1, false);
                a2 = __builtin_amdgcn_fdot2(cH[t + 2], RLh2(up, rlbase + t + 2), a2, false);
                a3 = __builtin_amdgcn_fdot2(cH[t + 3], RLh2(up, rlbase + t + 3), a3, false);
            }
            xb0[p][h][lane] = (a0 + a1) + (a2 + a3);
        }
        __syncthreads();
        // ---- v pair update: cols 2pl, 2pl+1 ----
        {
            const float2 a = *reinterpret_cast<const float2*>(&xb0[p][0][2 * pl]);
            const float2 b = *reinterpret_cast<const float2*>(&xb0[p][1][2 * pl]);
            float v0 = (float)vp.x, v1 = (float)vp.y;
            v0 = v0 * __builtin_amdgcn_rcpf(fmaf(v0, a.x + b.x, kEps));
            v1 = v1 * __builtin_amdgcn_rcpf(fmaf(v1, a.y + b.y, kEps));
            vp.x = (_Float16)v0; vp.y = (_Float16)v1;
        }
    }

    // ---- epilogue: out[r][lane] = u_r * K[r][lane] * v_lane ----
    __syncthreads();                       // xb0 reads above fully drained
    reinterpret_cast<h2*>(&xb0[p][0][0])[pl] = vp;   // v pairs -> LDS
    __syncthreads();
    const float vf = (float)reinterpret_cast<const _Float16*>(&xb0[p][0][0])[lane];

#pragma unroll
    for (int t = 0; t < 16; ++t) {
        const h2 u2 = RLh2(up, rlbase + t);          // u_{32h+2t}, u_{32h+2t+1}
        O[((32 * h + 2 * t + 0) << 6) + lane] = (float)u2.x * (float)cH[t].x * vf;
        O[((32 * h + 2 * t + 1) << 6) + lane] = (float)u2.y * (float)cH[t].y * vf;
    }
}

extern "C" void kernel_launch(void* const* d_in, const int* in_sizes, int n_in,
                              void* d_out, int out_size, void* d_ws, size_t ws_size,
                              hipStream_t stream) {
    const float* in = (const float*)d_in[0];
    float* out      = (float*)d_out;
    // 8192 matrices, 2 matrices per 256-thread (4-wave) block.
    sinkhorn64_h2<<<4096, 256, 0, stream>>>(in, out);
}

// Round 15
// 93.016 us; speedup vs baseline: 1.2657x; 1.2657x over previous
//
#include <hip/hip_runtime.h>

// Sinkhorn on 8192 independent 64x64 f32 matrices, 2 waves/matrix,
// 2 matrices per 256-thread block (R10 skeleton). Whole 20-iter loop in ONE
// asm block so the 64 K-floats are VGPR-resident operands for its entire
// lifetime (R9/R12 showed the allocator otherwise AGPR-homes them and pays
// per-use moves). R14 NaN fixes:
//   * s_nop after v_rcp_f32 before dependent v_mul (trans-op wait state --
//     the compiler inserts this in C codegen, hand asm must too)
//   * loop counter in s68 (R14's s33 could be clang's reserved FP/SP)
//   * no physical v clobbers: all temps are named "=&v" operands
// Per iteration/phase: 32 readlane -> s36..s67, 4 pk_mul + 12 pk_fma +
// 3 pk_add, ds_write_b64, barrier, 4x ds_read_b32, update (fma/rcp/mul).

static constexpr float kEps = 1e-6f;

__device__ __forceinline__ float RLf(float x, int l) {
    return __int_as_float(__builtin_amdgcn_readlane(__float_as_int(x), l));
}

__global__ __launch_bounds__(256) void sinkhorn64_asm2(const float* __restrict__ in,
                                                       float* __restrict__ out) {
    __shared__ float2 xw[2][2][64];   // K*v   partial pairs [p][h][lane]
    __shared__ float2 xt[2][2][64];   // K^T*u partial pairs
    __shared__ float  mbuf[2][2][64]; // prologue max exchange / v unrotate
    const int tid  = threadIdx.x;
    const int wid  = tid >> 6;
    const int p    = wid >> 1;               // matrix within block
    const int h    = wid & 1;                // half within matrix
    const int lane = tid & 63;
    const int c    = (lane + 32 * h) & 63;   // rotated index (self-inverse)
    const long m   = (long)blockIdx.x * 2 + p;
    const float* __restrict__ A = in  + m * 4096;
    float* __restrict__ O       = out + m * 4096;

    // ---- load K halves ----
    float cKf[32];
#pragma unroll
    for (int i = 0; i < 32; ++i) cKf[i] = A[((32 * h + i) << 6) + lane];
    float rKf[32];
#pragma unroll
    for (int k4 = 0; k4 < 8; ++k4) {
        const float4 f = *reinterpret_cast<const float4*>(A + (lane << 6) + 32 * h + (k4 << 2));
        rKf[4 * k4 + 0] = f.x; rKf[4 * k4 + 1] = f.y;
        rKf[4 * k4 + 2] = f.z; rKf[4 * k4 + 3] = f.w;
    }

    // ---- row max exchange + exp ----
    float pm = rKf[0];
#pragma unroll
    for (int k = 1; k < 32; ++k) pm = fmaxf(pm, rKf[k]);
    mbuf[p][h][lane] = pm;
    __syncthreads();
    const float mx  = fmaxf(pm, mbuf[p][1 - h][lane]);      // max of row `lane`
    const float mxr = fmaxf(mbuf[p][0][c], mbuf[p][1][c]);  // max of row `c`

    float2 rK2[16], cK2[16];
#pragma unroll
    for (int t = 0; t < 16; ++t) {
        rK2[t].x = __expf(rKf[2 * t + 0] - mx);
        rK2[t].y = __expf(rKf[2 * t + 1] - mx);
        cK2[t].x = __expf(cKf[2 * t + 0] - RLf(mxr, 2 * t + 0));
        cK2[t].y = __expf(cKf[2 * t + 1] - RLf(mxr, 2 * t + 1));
    }

    float ur = 1.0f, vr = 1.0f;
    const float epsv = kEps;

    // LDS byte offsets (gfx9 apertures are 2^32-aligned: low 32 bits of a
    // flat shared address ARE the LDS byte offset).
    const unsigned wa = (unsigned)(size_t)&xw[p][h][lane];
    const unsigned ra = (unsigned)(size_t)&xw[p][0][c];
    const unsigned wb = (unsigned)(size_t)&xt[p][h][lane];
    const unsigned rb = (unsigned)(size_t)&xt[p][0][c];

    float2 a0, a1, a2, a3;      // pk accumulators (compiler-allocated pairs)
    float  t0, t1, t2, t3;      // scalar temps

    asm volatile(
        "s_movk_i32 s68, 20\n"
        "1:\n"
        // ================= phase A: w-partial = rK . v =================
        "v_readlane_b32 s36, %[vr], 0\n"  "v_readlane_b32 s37, %[vr], 1\n"
        "v_readlane_b32 s38, %[vr], 2\n"  "v_readlane_b32 s39, %[vr], 3\n"
        "v_readlane_b32 s40, %[vr], 4\n"  "v_readlane_b32 s41, %[vr], 5\n"
        "v_readlane_b32 s42, %[vr], 6\n"  "v_readlane_b32 s43, %[vr], 7\n"
        "v_readlane_b32 s44, %[vr], 8\n"  "v_readlane_b32 s45, %[vr], 9\n"
        "v_readlane_b32 s46, %[vr], 10\n" "v_readlane_b32 s47, %[vr], 11\n"
        "v_readlane_b32 s48, %[vr], 12\n" "v_readlane_b32 s49, %[vr], 13\n"
        "v_readlane_b32 s50, %[vr], 14\n" "v_readlane_b32 s51, %[vr], 15\n"
        "v_readlane_b32 s52, %[vr], 16\n" "v_readlane_b32 s53, %[vr], 17\n"
        "v_readlane_b32 s54, %[vr], 18\n" "v_readlane_b32 s55, %[vr], 19\n"
        "v_readlane_b32 s56, %[vr], 20\n" "v_readlane_b32 s57, %[vr], 21\n"
        "v_readlane_b32 s58, %[vr], 22\n" "v_readlane_b32 s59, %[vr], 23\n"
        "v_readlane_b32 s60, %[vr], 24\n" "v_readlane_b32 s61, %[vr], 25\n"
        "v_readlane_b32 s62, %[vr], 26\n" "v_readlane_b32 s63, %[vr], 27\n"
        "v_readlane_b32 s64, %[vr], 28\n" "v_readlane_b32 s65, %[vr], 29\n"
        "v_readlane_b32 s66, %[vr], 30\n" "v_readlane_b32 s67, %[vr], 31\n"
        "v_pk_mul_f32 %[a0], s[36:37], %[r0]\n"
        "v_pk_mul_f32 %[a1], s[38:39], %[r1]\n"
        "v_pk_mul_f32 %[a2], s[40:41], %[r2]\n"
        "v_pk_mul_f32 %[a3], s[42:43], %[r3]\n"
        "v_pk_fma_f32 %[a0], s[44:45], %[r4], %[a0]\n"
        "v_pk_fma_f32 %[a1], s[46:47], %[r5], %[a1]\n"
        "v_pk_fma_f32 %[a2], s[48:49], %[r6], %[a2]\n"
        "v_pk_fma_f32 %[a3], s[50:51], %[r7], %[a3]\n"
        "v_pk_fma_f32 %[a0], s[52:53], %[r8], %[a0]\n"
        "v_pk_fma_f32 %[a1], s[54:55], %[r9], %[a1]\n"
        "v_pk_fma_f32 %[a2], s[56:57], %[r10], %[a2]\n"
        "v_pk_fma_f32 %[a3], s[58:59], %[r11], %[a3]\n"
        "v_pk_fma_f32 %[a0], s[60:61], %[r12], %[a0]\n"
        "v_pk_fma_f32 %[a1], s[62:63], %[r13], %[a1]\n"
        "v_pk_fma_f32 %[a2], s[64:65], %[r14], %[a2]\n"
        "v_pk_fma_f32 %[a3], s[66:67], %[r15], %[a3]\n"
        "v_pk_add_f32 %[a0], %[a0], %[a1]\n"
        "v_pk_add_f32 %[a2], %[a2], %[a3]\n"
        "v_pk_add_f32 %[a0], %[a0], %[a2]\n"
        "ds_write_b64 %[wa], %[a0]\n"
        "s_waitcnt lgkmcnt(0)\n"
        "s_barrier\n"
        "ds_read_b32 %[t0], %[ra] offset:0\n"
        "ds_read_b32 %[t1], %[ra] offset:4\n"
        "ds_read_b32 %[t2], %[ra] offset:512\n"
        "ds_read_b32 %[t3], %[ra] offset:516\n"
        "s_waitcnt lgkmcnt(0)\n"
        "v_add_f32 %[t0], %[t0], %[t1]\n"
        "v_add_f32 %[t2], %[t2], %[t3]\n"
        "v_add_f32 %[t0], %[t0], %[t2]\n"
        "v_fma_f32 %[t1], %[ur], %[t0], %[eps]\n"
        "v_rcp_f32 %[t1], %[t1]\n"
        "s_nop 1\n"
        "v_mul_f32 %[ur], %[ur], %[t1]\n"
        "s_nop 1\n"
        // ================= phase B: t-partial = cK . u =================
        "v_readlane_b32 s36, %[ur], 0\n"  "v_readlane_b32 s37, %[ur], 1\n"
        "v_readlane_b32 s38, %[ur], 2\n"  "v_readlane_b32 s39, %[ur], 3\n"
        "v_readlane_b32 s40, %[ur], 4\n"  "v_readlane_b32 s41, %[ur], 5\n"
        "v_readlane_b32 s42, %[ur], 6\n"  "v_readlane_b32 s43, %[ur], 7\n"
        "v_readlane_b32 s44, %[ur], 8\n"  "v_readlane_b32 s45, %[ur], 9\n"
        "v_readlane_b32 s46, %[ur], 10\n" "v_readlane_b32 s47, %[ur], 11\n"
        "v_readlane_b32 s48, %[ur], 12\n" "v_readlane_b32 s49, %[ur], 13\n"
        "v_readlane_b32 s50, %[ur], 14\n" "v_readlane_b32 s51, %[ur], 15\n"
        "v_readlane_b32 s52, %[ur], 16\n" "v_readlane_b32 s53, %[ur], 17\n"
        "v_readlane_b32 s54, %[ur], 18\n" "v_readlane_b32 s55, %[ur], 19\n"
        "v_readlane_b32 s56, %[ur], 20\n" "v_readlane_b32 s57, %[ur], 21\n"
        "v_readlane_b32 s58, %[ur], 22\n" "v_readlane_b32 s59, %[ur], 23\n"
        "v_readlane_b32 s60, %[ur], 24\n" "v_readlane_b32 s61, %[ur], 25\n"
        "v_readlane_b32 s62, %[ur], 26\n" "v_readlane_b32 s63, %[ur], 27\n"
        "v_readlane_b32 s64, %[ur], 28\n" "v_readlane_b32 s65, %[ur], 29\n"
        "v_readlane_b32 s66, %[ur], 30\n" "v_readlane_b32 s67, %[ur], 31\n"
        "v_pk_mul_f32 %[a0], s[36:37], %[c0]\n"
        "v_pk_mul_f32 %[a1], s[38:39], %[c1]\n"
        "v_pk_mul_f32 %[a2], s[40:41], %[c2]\n"
        "v_pk_mul_f32 %[a3], s[42:43], %[c3]\n"
        "v_pk_fma_f32 %[a0], s[44:45], %[c4], %[a0]\n"
        "v_pk_fma_f32 %[a1], s[46:47], %[c5], %[a1]\n"
        "v_pk_fma_f32 %[a2], s[48:49], %[c6], %[a2]\n"
        "v_pk_fma_f32 %[a3], s[50:51], %[c7], %[a3]\n"
        "v_pk_fma_f32 %[a0], s[52:53], %[c8], %[a0]\n"
        "v_pk_fma_f32 %[a1], s[54:55], %[c9], %[a1]\n"
        "v_pk_fma_f32 %[a2], s[56:57], %[c10], %[a2]\n"
        "v_pk_fma_f32 %[a3], s[58:59], %[c11], %[a3]\n"
        "v_pk_fma_f32 %[a0], s[60:61], %[c12], %[a0]\n"
        "v_pk_fma_f32 %[a1], s[62:63], %[c13], %[a1]\n"
        "v_pk_fma_f32 %[a2], s[64:65], %[c14], %[a2]\n"
        "v_pk_fma_f32 %[a3], s[66:67], %[c15], %[a3]\n"
        "v_pk_add_f32 %[a0], %[a0], %[a1]\n"
        "v_pk_add_f32 %[a2], %[a2], %[a3]\n"
        "v_pk_add_f32 %[a0], %[a0], %[a2]\n"
        "ds_write_b64 %[wb], %[a0]\n"
        "s_waitcnt lgkmcnt(0)\n"
        "s_barrier\n"
        "ds_read_b32 %[t0], %[rb] offset:0\n"
        "ds_read_b32 %[t1], %[rb] offset:4\n"
        "ds_read_b32 %[t2], %[rb] offset:512\n"
        "ds_read_b32 %[t3], %[rb] offset:516\n"
        "s_waitcnt lgkmcnt(0)\n"
        "v_add_f32 %[t0], %[t0], %[t1]\n"
        "v_add_f32 %[t2], %[t2], %[t3]\n"
        "v_add_f32 %[t0], %[t0], %[t2]\n"
        "v_fma_f32 %[t1], %[vr], %[t0], %[eps]\n"
        "v_rcp_f32 %[t1], %[t1]\n"
        "s_nop 1\n"
        "v_mul_f32 %[vr], %[vr], %[t1]\n"
        // ---- loop control (3 SALU slots also cover vr->readlane hazard) ----
        "s_sub_u32 s68, s68, 1\n"
        "s_cmp_lg_u32 s68, 0\n"
        "s_cbranch_scc1 1b\n"
        : [ur] "+v"(ur), [vr] "+v"(vr),
          [a0] "=&v"(a0), [a1] "=&v"(a1), [a2] "=&v"(a2), [a3] "=&v"(a3),
          [t0] "=&v"(t0), [t1] "=&v"(t1), [t2] "=&v"(t2), [t3] "=&v"(t3)
        : [r0] "v"(rK2[0]),  [r1] "v"(rK2[1]),  [r2] "v"(rK2[2]),  [r3] "v"(rK2[3]),
          [r4] "v"(rK2[4]),  [r5] "v"(rK2[5]),  [r6] "v"(rK2[6]),  [r7] "v"(rK2[7]),
          [r8] "v"(rK2[8]),  [r9] "v"(rK2[9]),  [r10] "v"(rK2[10]), [r11] "v"(rK2[11]),
          [r12] "v"(rK2[12]), [r13] "v"(rK2[13]), [r14] "v"(rK2[14]), [r15] "v"(rK2[15]),
          [c0] "v"(cK2[0]),  [c1] "v"(cK2[1]),  [c2] "v"(cK2[2]),  [c3] "v"(cK2[3]),
          [c4] "v"(cK2[4]),  [c5] "v"(cK2[5]),  [c6] "v"(cK2[6]),  [c7] "v"(cK2[7]),
          [c8] "v"(cK2[8]),  [c9] "v"(cK2[9]),  [c10] "v"(cK2[10]), [c11] "v"(cK2[11]),
          [c12] "v"(cK2[12]), [c13] "v"(cK2[13]), [c14] "v"(cK2[14]), [c15] "v"(cK2[15]),
          [wa] "v"(wa), [ra] "v"(ra), [wb] "v"(wb), [rb] "v"(rb), [eps] "v"(epsv)
        : "s36","s37","s38","s39","s40","s41","s42","s43",
          "s44","s45","s46","s47","s48","s49","s50","s51",
          "s52","s53","s54","s55","s56","s57","s58","s59",
          "s60","s61","s62","s63","s64","s65","s66","s67","s68",
          "scc","memory");

    // ---- epilogue: unrotate v, write O = diag(u) K diag(v) ----
    __syncthreads();
    mbuf[p][h][lane] = vr;
    __syncthreads();
    const float vfin = mbuf[p][0][lane];

#pragma unroll
    for (int t = 0; t < 16; ++t) {
        O[((32 * h + 2 * t + 0) << 6) + lane] = RLf(ur, 2 * t + 0) * cK2[t].x * vfin;
        O[((32 * h + 2 * t + 1) << 6) + lane] = RLf(ur, 2 * t + 1) * cK2[t].y * vfin;
    }
}

extern "C" void kernel_launch(void* const* d_in, const int* in_sizes, int n_in,
                              void* d_out, int out_size, void* d_ws, size_t ws_size,
                              hipStream_t stream) {
    const float* in = (const float*)d_in[0];
    float* out      = (float*)d_out;
    // 8192 matrices, 2 matrices per 256-thread (4-wave) block.
    sinkhorn64_asm2<<<4096, 256, 0, stream>>>(in, out);
}